// Round 1
// baseline (8246.719 us; speedup 1.0000x reference)
//
#include <hip/hip_runtime.h>
#include <stdint.h>

#define D 1024

typedef unsigned long long u64;
typedef unsigned int u32;

// ---------- monotonic float<->uint mapping for atomic max ----------
__device__ __forceinline__ u32 enc_f(float f) {
    u32 b = __float_as_uint(f);
    return (b & 0x80000000u) ? ~b : (b | 0x80000000u);
}
__device__ __forceinline__ float dec_f(u32 u) {
    u32 b = (u & 0x80000000u) ? (u ^ 0x80000000u) : ~u;
    return __uint_as_float(b);
}

// ---------- kernel A: max(X), max|X| ----------
__global__ void k_maxred(const float* __restrict__ X, u32* scal) {
    float mx = -INFINITY, ma = 0.f;
    int stride = gridDim.x * blockDim.x;
    for (int i = blockIdx.x * blockDim.x + threadIdx.x; i < D * D; i += stride) {
        float v = X[i];
        mx = fmaxf(mx, v);
        ma = fmaxf(ma, fabsf(v));
    }
    for (int o = 32; o; o >>= 1) {
        mx = fmaxf(mx, __shfl_xor(mx, o));
        ma = fmaxf(ma, __shfl_xor(ma, o));
    }
    if ((threadIdx.x & 63) == 0) {
        atomicMax(&scal[0], enc_f(mx));  // max_sim
        atomicMax(&scal[1], enc_f(ma));  // max|X|
    }
}

// ---------- kernel B: init dist (canonical symmetric) and cross (f64) ----------
__global__ void k_init(const float* __restrict__ X, const float* __restrict__ W,
                       float* __restrict__ dist, double* __restrict__ cross,
                       const u32* __restrict__ scal) {
    int idx = blockIdx.x * blockDim.x + threadIdx.x;
    if (idx >= D * D) return;
    float max_sim = dec_f(scal[0]);
    float MAXD = __fmul_rn(dec_f(scal[1]), 1000.0f);
    int i = idx >> 10, j = idx & (D - 1);
    float x = X[idx];
    // X is bitwise symmetric (0.5*(A+A^T)), so this matches max_sim - X[min][max]
    dist[idx] = (i == j) ? MAXD : __fsub_rn(max_sim, x);
    cross[idx] = (i == j) ? 0.0 : ((double)W[idx] + (double)W[j * D + i]);
}

// ---------- kernel B2: initial per-row (min,argmin) over upper triangle ----------
__global__ void k_rowmin(const float* __restrict__ dist, float* __restrict__ values_g,
                         int* __restrict__ indices_g, const u32* __restrict__ scal) {
    int r = blockIdx.x;
    int lane = threadIdx.x;  // 64 threads = 1 wave
    float MAXD = __fmul_rn(dec_f(scal[1]), 1000.0f);
    u64 best = ((u64)__float_as_uint(MAXD) << 32);  // (MAXD, idx 0) like jnp.argmin on all-MAXD row
    const float* row = dist + (size_t)r * D;
    for (int j = lane; j < D; j += 64) {
        if (j > r) {
            u64 k = ((u64)__float_as_uint(row[j]) << 32) | (u32)j;
            if (k < best) best = k;
        }
    }
    for (int o = 32; o; o >>= 1) {
        u64 k2 = __shfl_xor(best, o);
        if (k2 < best) best = k2;
    }
    if (lane == 0) {
        values_g[r] = __uint_as_float((u32)(best >> 32));
        indices_g[r] = (int)(best & 0xffffffffu);
    }
}

// ---------- kernel C: persistent single-block HAC loop ----------
__global__ void __launch_bounds__(1024) k_hac(
        float* __restrict__ dist, double* __restrict__ cross,
        const float* __restrict__ values_g, const int* __restrict__ indices_g,
        int* __restrict__ labels_g, const u32* __restrict__ scal) {
    __shared__ float values_l[D];
    __shared__ int indices_l[D];
    __shared__ float newv_l[D];
    __shared__ float cs_l[D];
    __shared__ unsigned char dead_l[D];
    __shared__ int slot_l[D];   // slot_of_leaf
    __shared__ int label_l[D];
    __shared__ double within_l[D];
    __shared__ double energy_l[D];
    __shared__ int rlist[D];
    __shared__ int nrec;
    __shared__ u64 wkeys[16];
    __shared__ int s_m1, s_m2, s_take;
    __shared__ float s_cs1, s_cs2, s_ncs;
    __shared__ double s_cross12;

    const int t = threadIdx.x;
    const int lane = t & 63, wid = t >> 6;
    const float MAXD = __fmul_rn(dec_f(scal[1]), 1000.0f);
    const u32 MAXDb = __float_as_uint(MAXD);

    values_l[t] = values_g[t];
    indices_l[t] = indices_g[t];
    cs_l[t] = 1.0f;
    dead_l[t] = 0;
    slot_l[t] = t;
    label_l[t] = t;
    within_l[t] = 0.0;
    energy_l[t] = 0.0;
    __syncthreads();

    for (int it = 0; it < D - 1; ++it) {
        // ---- P1: global argmin over values (lowest-index tie-break) ----
        u64 key = ((u64)__float_as_uint(values_l[t]) << 32) | (u32)t;
        for (int o = 32; o; o >>= 1) {
            u64 k2 = __shfl_xor(key, o);
            if (k2 < key) key = k2;
        }
        if (lane == 0) wkeys[wid] = key;
        __syncthreads();
        if (wid == 0) {
            u64 k = (lane < 16) ? wkeys[lane] : ~0ull;
            for (int o = 8; o; o >>= 1) {
                u64 k2 = __shfl_xor(k, o);
                if (k2 < k) k = k2;
            }
            if (lane == 0) {
                int m1 = (int)(k & 0xffffffffu);
                int m2 = indices_l[m1];
                s_m1 = m1;
                s_m2 = m2;
                float c1 = cs_l[m1], c2 = cs_l[m2];
                s_cs1 = c1;
                s_cs2 = c2;
                s_ncs = __fadd_rn(c1, c2);
            }
        }
        __syncthreads();
        const int m1 = s_m1, m2 = s_m2;
        const float cs1 = s_cs1, cs2 = s_cs2, ncs = s_ncs;

        // ---- P2: merged distances + cross-row merge (thread t == column j) ----
        {
            const int j = t;
            float d1 = dist[m1 * D + j];
            float d2 = dist[m2 * D + j];
            double c1 = cross[(size_t)m1 * D + j];
            double c2 = cross[(size_t)m2 * D + j];
            float nv;
            if (dead_l[j] || j == m1 || j == m2)
                nv = MAXD;  // reference max_mask restore / col-m2 retire
            else
                nv = __fdiv_rn(__fadd_rn(__fmul_rn(d1, cs1), __fmul_rn(d2, cs2)), ncs);
            newv_l[j] = nv;
            dist[m1 * D + j] = nv;
            dist[j * D + m1] = nv;
            dist[m2 * D + j] = MAXD;
            dist[j * D + m2] = MAXD;
            double cd = c1 + c2;
            cross[(size_t)m1 * D + j] = cd;
            cross[(size_t)j * D + m1] = cd;
            if (j == m2) s_cross12 = c1;  // old cross(m1,m2)
            if (j == 0) nrec = 0;
        }
        __syncthreads();

        // ---- P2.5: scalar merge bookkeeping + cut decision ----
        if (t == 0) {
            double merge_e = within_l[m1] + within_l[m2] + s_cross12;
            double e_sum = energy_l[m1] + energy_l[m2];
            int take = (merge_e >= e_sum) ? 1 : 0;
            within_l[m1] = merge_e;
            energy_l[m1] = take ? merge_e : e_sum;
            cs_l[m1] = ncs;
            dead_l[m2] = 1;
            values_l[m2] = MAXD;  // frozen (vmask)
            indices_l[m2] = 0;    // argmin of all-MAXD row
            s_take = take;
        }
        __syncthreads();

        // ---- P3+P4: leaf labels + incremental row-min maintenance ----
        {
            // leaf membership / label (thread t == leaf l)
            if (slot_l[t] == m2) slot_l[t] = m1;
            if (s_take && slot_l[t] == m1) label_l[t] = D + it;

            // row-min update (thread t == row r)
            const int r = t;
            float v = values_l[r];
            if (r == m1) {
                int p = atomicAdd(&nrec, 1);
                rlist[p] = r;  // row m1 fully rebuilt
            } else if (v < MAXD) {  // live, not frozen; m2 already frozen above
                int idx = indices_l[r];
                if (idx == m2) {  // min entry retired -> rescan
                    int p = atomicAdd(&nrec, 1);
                    rlist[p] = r;
                } else if (idx == m1) {  // implies r < m1
                    float nv = newv_l[r];
                    if (nv <= v)
                        values_l[r] = nv;  // argmin stays m1 (lowest-tie preserved)
                    else {
                        int p = atomicAdd(&nrec, 1);
                        rlist[p] = r;  // min may have increased
                    }
                } else if (r < m1) {  // col m1 got newv[r]
                    float nv = newv_l[r];
                    if (nv < v) {
                        values_l[r] = nv;
                        indices_l[r] = m1;
                    } else if (nv == v && m1 < idx) {
                        indices_l[r] = m1;  // jnp.argmin lowest-index tie-break
                    }
                }
                // rows with m1 < r, idx not in {m1,m2}: unchanged (col m1/m2 not in row r or masked)
            }
        }
        __syncthreads();

        // ---- P5: full rescans, one wave per row ----
        {
            const int n = nrec;
            for (int q = wid; q < n; q += 16) {
                const int r = rlist[q];
                u64 best = ((u64)MAXDb << 32);  // (MAXD, 0)
                const float* row = dist + (size_t)r * D;
                for (int j = lane; j < D; j += 64) {
                    if (j > r) {
                        u64 k = ((u64)__float_as_uint(row[j]) << 32) | (u32)j;
                        if (k < best) best = k;
                    }
                }
                for (int o = 32; o; o >>= 1) {
                    u64 k2 = __shfl_xor(best, o);
                    if (k2 < best) best = k2;
                }
                if (lane == 0) {
                    values_l[r] = __uint_as_float((u32)(best >> 32));
                    indices_l[r] = (int)(best & 0xffffffffu);
                }
            }
        }
        __syncthreads();
    }

    labels_g[t] = label_l[t];
}

// ---------- kernel D: R[a][b] = (a==b) || (label[a]==label[b]) ----------
__global__ void k_out(const int* __restrict__ labels, float* __restrict__ out) {
    int idx = blockIdx.x * blockDim.x + threadIdx.x;
    if (idx >= D * D) return;
    int i = idx >> 10, j = idx & (D - 1);
    out[idx] = (i == j || labels[i] == labels[j]) ? 1.0f : 0.0f;
}

extern "C" void kernel_launch(void* const* d_in, const int* in_sizes, int n_in,
                              void* d_out, int out_size, void* d_ws, size_t ws_size,
                              hipStream_t stream) {
    const float* X = (const float*)d_in[0];
    const float* W = (const float*)d_in[1];

    // dist lives in d_out during the build; k_out overwrites it at the end.
    float* dist = (float*)d_out;

    char* ws = (char*)d_ws;
    const size_t CROSS_BYTES = (size_t)D * D * sizeof(double);  // 8 MiB
    double* cross = (double*)ws;
    float* values_g = (float*)(ws + CROSS_BYTES);
    int* indices_g = (int*)(ws + CROSS_BYTES + 4096);
    int* labels_g = (int*)(ws + CROSS_BYTES + 8192);
    u32* scal = (u32*)(ws + CROSS_BYTES + 12288);

    hipMemsetAsync(scal, 0, 2 * sizeof(u32), stream);
    k_maxred<<<256, 256, 0, stream>>>(X, scal);
    k_init<<<(D * D) / 256, 256, 0, stream>>>(X, W, dist, cross, scal);
    k_rowmin<<<D, 64, 0, stream>>>(dist, values_g, indices_g, scal);
    k_hac<<<1, 1024, 0, stream>>>(dist, cross, values_g, indices_g, labels_g, scal);
    k_out<<<(D * D) / 256, 256, 0, stream>>>(labels_g, (float*)d_out);
}

// Round 2
// 5770.026 us; speedup vs baseline: 1.4292x; 1.4292x over previous
//
#include <hip/hip_runtime.h>
#include <stdint.h>

#define D 1024

typedef unsigned long long u64;
typedef unsigned int u32;

// ---------- monotonic float<->uint mapping for atomic max ----------
__device__ __forceinline__ u32 enc_f(float f) {
    u32 b = __float_as_uint(f);
    return (b & 0x80000000u) ? ~b : (b | 0x80000000u);
}
__device__ __forceinline__ float dec_f(u32 u) {
    u32 b = (u & 0x80000000u) ? (u ^ 0x80000000u) : ~u;
    return __uint_as_float(b);
}

// ---------- kernel A: max(X), max|X| ----------
__global__ void k_maxred(const float* __restrict__ X, u32* scal) {
    float mx = -INFINITY, ma = 0.f;
    int stride = gridDim.x * blockDim.x;
    for (int i = blockIdx.x * blockDim.x + threadIdx.x; i < D * D; i += stride) {
        float v = X[i];
        mx = fmaxf(mx, v);
        ma = fmaxf(ma, fabsf(v));
    }
    for (int o = 32; o; o >>= 1) {
        mx = fmaxf(mx, __shfl_xor(mx, o));
        ma = fmaxf(ma, __shfl_xor(ma, o));
    }
    if ((threadIdx.x & 63) == 0) {
        atomicMax(&scal[0], enc_f(mx));  // max_sim
        atomicMax(&scal[1], enc_f(ma));  // max|X|
    }
}

// ---------- kernel B: init packed (dist, cross) float2 matrix ----------
// pc[i*D+j] = (Y(i,j) canonical-symmetric, cross(i,j) = W[i,j]+W[j,i] exact in f32
//              since W is strictly upper-triangular)
__global__ void k_init(const float* __restrict__ X, const float* __restrict__ W,
                       float2* __restrict__ pc, const u32* __restrict__ scal) {
    int idx = blockIdx.x * blockDim.x + threadIdx.x;
    if (idx >= D * D) return;
    float max_sim = dec_f(scal[0]);
    float MAXD = __fmul_rn(dec_f(scal[1]), 1000.0f);
    int i = idx >> 10, j = idx & (D - 1);
    float x = X[idx];
    // X is bitwise symmetric (0.5*(A+A^T)), so this matches max_sim - X[min][max]
    float d = (i == j) ? MAXD : __fsub_rn(max_sim, x);
    float c = (i == j) ? 0.0f : (W[idx] + W[j * D + i]);  // one addend is exactly 0
    pc[idx] = make_float2(d, c);
}

// ---------- kernel B2: initial per-row (min,argmin) over upper triangle ----------
__global__ void k_rowmin(const float2* __restrict__ pc, float* __restrict__ values_g,
                         int* __restrict__ indices_g, const u32* __restrict__ scal) {
    int r = blockIdx.x;
    int lane = threadIdx.x;  // 64 threads = 1 wave
    float MAXD = __fmul_rn(dec_f(scal[1]), 1000.0f);
    u64 best = ((u64)__float_as_uint(MAXD) << 32);  // (MAXD, idx 0) like jnp.argmin on all-MAXD row
    const float2* row = pc + (size_t)r * D;
    for (int j = lane; j < D; j += 64) {
        if (j > r) {
            u64 k = ((u64)__float_as_uint(row[j].x) << 32) | (u32)j;
            if (k < best) best = k;
        }
    }
    for (int o = 32; o; o >>= 1) {
        u64 k2 = __shfl_xor(best, o);
        if (k2 < best) best = k2;
    }
    if (lane == 0) {
        values_g[r] = __uint_as_float((u32)(best >> 32));
        indices_g[r] = (int)(best & 0xffffffffu);
    }
}

// ---------- kernel C: persistent single-block HAC loop, 3 barriers/iter ----------
__global__ void __launch_bounds__(1024) k_hac(
        float2* __restrict__ pc,
        const float* __restrict__ values_g, const int* __restrict__ indices_g,
        int* __restrict__ labels_g, const u32* __restrict__ scal) {
    __shared__ __align__(16) float values_l[D];
    __shared__ int indices_l[D];
    __shared__ float cs_l[D];
    __shared__ unsigned char dead_l[D];
    __shared__ int slot_l[D];   // slot_of_leaf
    __shared__ int label_l[D];
    __shared__ double within_l[D];
    __shared__ double energy_l[D];
    __shared__ int rlist[D];
    __shared__ int nrec;
    __shared__ int s_m1, s_m2;
    __shared__ float s_cs1, s_cs2, s_ncs, s_cross12;
    __shared__ int s_takeP, s_m1P, s_labP;  // deferred cut decision (applied next iter)

    const int t = threadIdx.x;
    const int lane = t & 63, wid = t >> 6;
    const float MAXD = __fmul_rn(dec_f(scal[1]), 1000.0f);
    const u32 MAXDb = __float_as_uint(MAXD);

    values_l[t] = values_g[t];
    indices_l[t] = indices_g[t];
    cs_l[t] = 1.0f;
    dead_l[t] = 0;
    slot_l[t] = t;
    label_l[t] = t;
    within_l[t] = 0.0;
    energy_l[t] = 0.0;
    if (t == 0) { s_takeP = 0; s_m1P = -1; s_labP = 0; }
    __syncthreads();  // B0 for it=0

    for (int it = 0; it < D - 1; ++it) {
        // ---- P1 (wave0 only): global argmin over values + merge bookkeeping ----
        if (wid == 0) {
            const float4* v4 = (const float4*)values_l;
            u64 best = ~0ull;
#pragma unroll
            for (int c = 0; c < 4; ++c) {
                int fi = lane + 64 * c;
                float4 q = v4[fi];
                int b = fi << 2;
                u64 k;
                k = ((u64)__float_as_uint(q.x) << 32) | (u32)(b + 0); if (k < best) best = k;
                k = ((u64)__float_as_uint(q.y) << 32) | (u32)(b + 1); if (k < best) best = k;
                k = ((u64)__float_as_uint(q.z) << 32) | (u32)(b + 2); if (k < best) best = k;
                k = ((u64)__float_as_uint(q.w) << 32) | (u32)(b + 3); if (k < best) best = k;
            }
            for (int o = 32; o; o >>= 1) {
                u64 k2 = __shfl_xor(best, o);
                if (k2 < best) best = k2;
            }
            if (lane == 0) {
                int m1 = (int)(best & 0xffffffffu);
                int m2 = indices_l[m1];   // m2 > m1 always (upper-tri argmin)
                s_m1 = m1;
                s_m2 = m2;
                float c1 = cs_l[m1], c2 = cs_l[m2];
                s_cs1 = c1;
                s_cs2 = c2;
                float nc = __fadd_rn(c1, c2);
                s_ncs = nc;
                cs_l[m1] = nc;
                dead_l[m2] = 1;
                values_l[m2] = MAXD;  // vmask freeze
                indices_l[m2] = 0;    // argmin of all-MAXD row
                nrec = 0;
            }
        }
        __syncthreads();  // B1

        const int m1 = s_m1, m2 = s_m2;
        const float cs1 = s_cs1, cs2 = s_cs2, ncs = s_ncs;

        // ---- P2: deferred label apply + slot merge + merged (dist,cross) update
        //          + incremental row-min maintenance (all fused, thread t owns row/col/leaf t)
        {
            int sl = slot_l[t];
            if (s_takeP && sl == s_m1P) label_l[t] = s_labP;  // apply previous iter's cut
            if (sl == m2) slot_l[t] = m1;                     // merge membership
        }
        bool alive = !dead_l[t];
        float nv = MAXD;
        {
            float2 pd1, pd2;
            if (alive || t == m2) {
                pd1 = pc[(size_t)m1 * D + t];
                pd2 = pc[(size_t)m2 * D + t];
            }
            if (t == m2) s_cross12 = pd1.y;  // old cross(m1,m2), consumed post-B2
            if (alive && t != m1) {
                nv = __fdiv_rn(__fadd_rn(__fmul_rn(pd1.x, cs1), __fmul_rn(pd2.x, cs2)), ncs);
                float ncx = pd1.y + pd2.y;
                float2 w = make_float2(nv, ncx);
                pc[(size_t)m1 * D + t] = w;  // row m1 (coalesced)
                pc[(size_t)t * D + m1] = w;  // col m1 (scattered, live-only)
            }
        }
        {
            float v = values_l[t];
            if (t == m1) {
                rlist[atomicAdd(&nrec, 1)] = t;        // row m1 fully rebuilt
            } else if (alive && v < MAXD) {            // live, not frozen
                int idx = indices_l[t];
                if (idx == m2) {
                    rlist[atomicAdd(&nrec, 1)] = t;    // min retired -> rescan
                } else if (idx == m1) {                // implies t < m1
                    if (nv <= v) values_l[t] = nv;     // lowest-index tie preserved
                    else rlist[atomicAdd(&nrec, 1)] = t;
                } else if (t < m1) {                   // col m1 got nv in row t
                    if (nv < v) { values_l[t] = nv; indices_l[t] = m1; }
                    else if (nv == v && m1 < idx) indices_l[t] = m1;  // jnp.argmin tie-break
                }
            }
        }
        __syncthreads();  // B2 (drains global writes; rlist/s_cross12 visible)

        // ---- P3: wave0 computes cut decision; waves 1..15 do full rescans ----
        {
            int n = nrec;
            if (wid == 0) {
                if (lane == 0) {
                    double merge_e = within_l[m1] + within_l[m2] + (double)s_cross12;
                    double e_sum = energy_l[m1] + energy_l[m2];
                    int take = (merge_e >= e_sum) ? 1 : 0;
                    within_l[m1] = merge_e;
                    energy_l[m1] = take ? merge_e : e_sum;
                    s_takeP = take;
                    s_m1P = m1;
                    s_labP = D + it;
                }
            } else {
                for (int q = wid - 1; q < n; q += 15) {
                    int r = rlist[q];
                    u64 best = ((u64)MAXDb << 32);  // (MAXD, 0)
                    const float2* row = pc + (size_t)r * D;
                    for (int j = lane; j < D; j += 64) {
                        if (j > r && !dead_l[j]) {
                            u64 k = ((u64)__float_as_uint(row[j].x) << 32) | (u32)j;
                            if (k < best) best = k;
                        }
                    }
                    for (int o = 32; o; o >>= 1) {
                        u64 k2 = __shfl_xor(best, o);
                        if (k2 < best) best = k2;
                    }
                    if (lane == 0) {
                        values_l[r] = __uint_as_float((u32)(best >> 32));
                        indices_l[r] = (int)(best & 0xffffffffu);
                    }
                }
            }
        }
        __syncthreads();  // B0 of next iter
    }

    // apply the final iteration's deferred cut, then emit labels
    {
        int sl = slot_l[t];
        int lab = label_l[t];
        if (s_takeP && sl == s_m1P) lab = s_labP;
        labels_g[t] = lab;
    }
}

// ---------- kernel D: R[a][b] = (a==b) || (label[a]==label[b]) ----------
__global__ void k_out(const int* __restrict__ labels, float* __restrict__ out) {
    int idx = blockIdx.x * blockDim.x + threadIdx.x;
    if (idx >= D * D) return;
    int i = idx >> 10, j = idx & (D - 1);
    out[idx] = (i == j || labels[i] == labels[j]) ? 1.0f : 0.0f;
}

extern "C" void kernel_launch(void* const* d_in, const int* in_sizes, int n_in,
                              void* d_out, int out_size, void* d_ws, size_t ws_size,
                              hipStream_t stream) {
    const float* X = (const float*)d_in[0];
    const float* W = (const float*)d_in[1];

    char* ws = (char*)d_ws;
    const size_t PC_BYTES = (size_t)D * D * sizeof(float2);  // 8 MiB
    float2* pc = (float2*)ws;
    float* values_g = (float*)(ws + PC_BYTES);
    int* indices_g = (int*)(ws + PC_BYTES + 4096);
    int* labels_g = (int*)(ws + PC_BYTES + 8192);
    u32* scal = (u32*)(ws + PC_BYTES + 12288);

    hipMemsetAsync(scal, 0, 2 * sizeof(u32), stream);
    k_maxred<<<256, 256, 0, stream>>>(X, scal);
    k_init<<<(D * D) / 256, 256, 0, stream>>>(X, W, pc, scal);
    k_rowmin<<<D, 64, 0, stream>>>(pc, values_g, indices_g, scal);
    k_hac<<<1, 1024, 0, stream>>>(pc, values_g, indices_g, labels_g, scal);
    k_out<<<(D * D) / 256, 256, 0, stream>>>(labels_g, (float*)d_out);
}

// Round 4
// 4931.309 us; speedup vs baseline: 1.6723x; 1.1701x over previous
//
#include <hip/hip_runtime.h>
#include <stdint.h>

#define D 1024

typedef unsigned long long u64;
typedef unsigned int u32;

// ---------- monotonic float<->uint mapping for atomic max ----------
__device__ __forceinline__ u32 enc_f(float f) {
    u32 b = __float_as_uint(f);
    return (b & 0x80000000u) ? ~b : (b | 0x80000000u);
}
__device__ __forceinline__ float dec_f(u32 u) {
    u32 b = (u & 0x80000000u) ? (u ^ 0x80000000u) : ~u;
    return __uint_as_float(b);
}

// ---------- kernel A: max(X), max|X| ----------
__global__ void k_maxred(const float* __restrict__ X, u32* scal) {
    float mx = -INFINITY, ma = 0.f;
    int stride = gridDim.x * blockDim.x;
    for (int i = blockIdx.x * blockDim.x + threadIdx.x; i < D * D; i += stride) {
        float v = X[i];
        mx = fmaxf(mx, v);
        ma = fmaxf(ma, fabsf(v));
    }
    for (int o = 32; o; o >>= 1) {
        mx = fmaxf(mx, __shfl_xor(mx, o));
        ma = fmaxf(ma, __shfl_xor(ma, o));
    }
    if ((threadIdx.x & 63) == 0) {
        atomicMax(&scal[0], enc_f(mx));  // max_sim
        atomicMax(&scal[1], enc_f(ma));  // max|X|
    }
}

// ---------- kernel B: init packed (dist, cross) float2 matrix ----------
__global__ void k_init(const float* __restrict__ X, const float* __restrict__ W,
                       float2* __restrict__ pc, const u32* __restrict__ scal) {
    int idx = blockIdx.x * blockDim.x + threadIdx.x;
    if (idx >= D * D) return;
    float max_sim = dec_f(scal[0]);
    float MAXD = __fmul_rn(dec_f(scal[1]), 1000.0f);
    int i = idx >> 10, j = idx & (D - 1);
    float x = X[idx];
    // X is bitwise symmetric (0.5*(A+A^T)), so this matches max_sim - X[min][max]
    float d = (i == j) ? MAXD : __fsub_rn(max_sim, x);
    float c = (i == j) ? 0.0f : (W[idx] + W[j * D + i]);  // one addend is exactly 0
    pc[idx] = make_float2(d, c);
}

// ---------- kernel B2: initial per-row (min,argmin) over upper triangle ----------
__global__ void k_rowmin(const float2* __restrict__ pc, float* __restrict__ values_g,
                         int* __restrict__ indices_g, const u32* __restrict__ scal) {
    int r = blockIdx.x;
    int lane = threadIdx.x;  // 64 threads = 1 wave
    float MAXD = __fmul_rn(dec_f(scal[1]), 1000.0f);
    u64 best = ((u64)__float_as_uint(MAXD) << 32);  // (MAXD, idx 0) like jnp.argmin on all-MAXD row
    const float2* row = pc + (size_t)r * D;
    for (int j = lane; j < D; j += 64) {
        if (j > r) {
            u64 k = ((u64)__float_as_uint(row[j].x) << 32) | (u32)j;
            if (k < best) best = k;
        }
    }
    for (int o = 32; o; o >>= 1) {
        u64 k2 = __shfl_xor(best, o);
        if (k2 < best) best = k2;
    }
    if (lane == 0) {
        values_g[r] = __uint_as_float((u32)(best >> 32));
        indices_g[r] = (int)(best & 0xffffffffu);
    }
}

// ---------- kernel C: persistent single-block HAC loop, 2 barriers/iter ----------
__global__ void __launch_bounds__(1024) k_hac(
        float2* __restrict__ pc,
        const float* __restrict__ values_g, const int* __restrict__ indices_g,
        int* __restrict__ labels_g, const u32* __restrict__ scal) {
    __shared__ __align__(16) float values_l[D];
    __shared__ int indices_l[D];
    __shared__ __align__(16) float2 newv_l[D];
    __shared__ float cs_l[D];
    __shared__ unsigned char dead_l[D];
    __shared__ int slot_l[D];   // slot_of_leaf
    __shared__ int label_l[D];
    __shared__ double within_l[D];
    __shared__ double energy_l[D];
    __shared__ int rlist[2][D];
    __shared__ int nrec[2];
    __shared__ u64 wkeys[16];
    __shared__ float s_cross12;
    __shared__ int s_takeP, s_m1P, s_labP;  // deferred cut decision (applied next iter)

    const int t = threadIdx.x;
    const int lane = t & 63, wid = t >> 6;
    const float MAXD = __fmul_rn(dec_f(scal[1]), 1000.0f);
    const u32 MAXDb = __float_as_uint(MAXD);

    values_l[t] = values_g[t];
    indices_l[t] = indices_g[t];
    cs_l[t] = 1.0f;
    dead_l[t] = 0;
    slot_l[t] = t;
    label_l[t] = t;
    within_l[t] = 0.0;
    energy_l[t] = 0.0;
    if (t == 0) { s_takeP = 0; s_m1P = -1; s_labP = 0; nrec[0] = 0; nrec[1] = 0; }
    __syncthreads();
    // boot: per-wave argmin over own 64 values -> wkeys (key = (value, row))
    {
        u64 key = ((u64)__float_as_uint(values_l[t]) << 32) | (u32)t;
        for (int o = 32; o; o >>= 1) {
            u64 k2 = __shfl_xor(key, o);
            if (k2 < key) key = k2;
        }
        if (lane == 0) wkeys[wid] = key;
    }
    __syncthreads();  // equivalent of B3 for it=0

    for (int it = 0; it < D - 1; ++it) {
        const int buf = it & 1;

        // ================= P2 =================
        // combine the 16 wave keys (broadcast LDS reads, every thread)
        u64 best = wkeys[0];
#pragma unroll
        for (int w = 1; w < 16; ++w) {
            u64 k = wkeys[w];
            if (k < best) best = k;
        }
        const int m1 = (int)(best & 0xffffffffu);
        const int m2 = indices_l[m1];  // m2 > m1 always (upper-tri argmin)
        const float cs1 = cs_l[m1], cs2 = cs_l[m2];
        const float ncs = __fadd_rn(cs1, cs2);

        // deferred label apply (prev iter's cut), then slot merge for this iter
        {
            int sl = slot_l[t];
            if (s_takeP && sl == s_m1P) label_l[t] = s_labP;
            if (sl == m2) slot_l[t] = m1;
        }
        // freeze m2 (own-thread writes only -> race-free)
        if (t == m2) {
            dead_l[m2] = 1;
            values_l[m2] = MAXD;  // vmask freeze
            indices_l[m2] = 0;    // argmin of all-MAXD row
        }
        const bool alive = !dead_l[t];  // thread m2 sees its own write

        float nv = MAXD;
        float2 wv;
        bool do_col = false;
        {
            float2 pd1, pd2;
            if (alive || t == m2) {
                pd1 = pc[(size_t)m1 * D + t];
                pd2 = pc[(size_t)m2 * D + t];
            }
            if (t == m2) s_cross12 = pd1.y;  // old cross(m1,m2), consumed post-B2
            if (alive && t != m1) {
                nv = __fdiv_rn(__fadd_rn(__fmul_rn(pd1.x, cs1), __fmul_rn(pd2.x, cs2)), ncs);
                wv = make_float2(nv, pd1.y + pd2.y);
                newv_l[t] = wv;                 // for rescan col-m1 redirect
                pc[(size_t)m1 * D + t] = wv;    // row m1 (coalesced)
                do_col = true;                  // col m1 store deferred to P3
            }
        }
        // incremental row-min maintenance (thread t == row t)
        {
            float v = values_l[t];
            if (t == m1) {
                rlist[buf][atomicAdd(&nrec[buf], 1)] = t;
                values_l[t] = MAXD;  // transient marker for wave0's argmin scan
            } else if (alive && v < MAXD) {
                int idx = indices_l[t];
                if (idx == m2) {
                    rlist[buf][atomicAdd(&nrec[buf], 1)] = t;
                    values_l[t] = MAXD;
                } else if (idx == m1) {  // implies t < m1
                    if (nv <= v) values_l[t] = nv;  // lowest-index tie preserved
                    else {
                        rlist[buf][atomicAdd(&nrec[buf], 1)] = t;
                        values_l[t] = MAXD;
                    }
                } else if (t < m1) {  // col m1 got nv in row t
                    if (nv < v) { values_l[t] = nv; indices_l[t] = m1; }
                    else if (nv == v && m1 < idx) indices_l[t] = m1;  // jnp.argmin tie-break
                }
            }
        }
        __syncthreads();  // B2 (publishes LDS; drains row loads/stores)

        // ================= P3 =================
        // scattered col store, issued first so its drain overlaps the rescans
        if (do_col) pc[(size_t)t * D + m1] = wv;
        if (t == m1) cs_l[m1] = ncs;  // nobody reads cs_l in P3
        const int n = nrec[buf];
        if (t == 0) nrec[1 - buf] = 0;

        u64 wkey = ~0ull;
        if (wid == 0) {
            if (lane == 0) {
                // cut decision (f64 accumulators)
                double merge_e = within_l[m1] + within_l[m2] + (double)s_cross12;
                double e_sum = energy_l[m1] + energy_l[m2];
                int take = (merge_e >= e_sum) ? 1 : 0;
                within_l[m1] = merge_e;
                energy_l[m1] = take ? merge_e : e_sum;
                s_takeP = take;
                s_m1P = m1;
                s_labP = D + it;
            }
            // full argmin scan of values_l (rescan rows are MAXD-marked; their true
            // keys arrive via the rescan waves' wkeys — min-combine is exact)
            const float4* v4 = (const float4*)values_l;
            u64 bb = ~0ull;
#pragma unroll
            for (int c = 0; c < 4; ++c) {
                int fi = lane + 64 * c;
                float4 q = v4[fi];
                int b = fi << 2;
                u64 k;
                k = ((u64)__float_as_uint(q.x) << 32) | (u32)(b + 0); if (k < bb) bb = k;
                k = ((u64)__float_as_uint(q.y) << 32) | (u32)(b + 1); if (k < bb) bb = k;
                k = ((u64)__float_as_uint(q.z) << 32) | (u32)(b + 2); if (k < bb) bb = k;
                k = ((u64)__float_as_uint(q.w) << 32) | (u32)(b + 3); if (k < bb) bb = k;
            }
            for (int o = 32; o; o >>= 1) {
                u64 k2 = __shfl_xor(bb, o);
                if (k2 < bb) bb = k2;
            }
            wkey = bb;
        } else {
            // full rescans, one wave per row, float4 loads (2 entries per load)
            for (int q = wid - 1; q < n; q += 15) {
                const int r = rlist[buf][q];
                const float subst = newv_l[r].x;  // col m1 redirect (in-flight in global)
                u64 bb = ((u64)MAXDb << 32);      // (MAXD, 0) -> row-local (value, col) key
                const float4* row4 = (const float4*)(pc + (size_t)r * D);
                for (int c = lane; c < D / 2; c += 64) {
                    float4 q4 = row4[c];
                    int j0 = 2 * c, j1 = 2 * c + 1;
                    float d0 = (j0 == m1) ? subst : q4.x;
                    float d1 = (j1 == m1) ? subst : q4.z;
                    if (j0 > r && !dead_l[j0]) {
                        u64 k = ((u64)__float_as_uint(d0) << 32) | (u32)j0;
                        if (k < bb) bb = k;
                    }
                    if (j1 > r && !dead_l[j1]) {
                        u64 k = ((u64)__float_as_uint(d1) << 32) | (u32)j1;
                        if (k < bb) bb = k;
                    }
                }
                for (int o = 32; o; o >>= 1) {
                    u64 k2 = __shfl_xor(bb, o);
                    if (k2 < bb) bb = k2;
                }
                if (lane == 0) {
                    values_l[r] = __uint_as_float((u32)(bb >> 32));
                    indices_l[r] = (int)(bb & 0xffffffffu);
                }
                // BUGFIX(R3): global-argmin key must carry the ROW index r (and
                // tie-break on lowest row), not the column index from bb.
                u64 rowkey = (bb & 0xffffffff00000000ull) | (u32)r;
                if (rowkey < wkey) wkey = rowkey;
            }
        }
        if (lane == 0) wkeys[wid] = wkey;
        __syncthreads();  // B3 (publishes argmin keys; drains col stores + rescan loads)
    }

    // apply the final iteration's deferred cut, then emit labels
    {
        int lab = label_l[t];
        if (s_takeP && slot_l[t] == s_m1P) lab = s_labP;
        labels_g[t] = lab;
    }
}

// ---------- kernel D: R[a][b] = (a==b) || (label[a]==label[b]) ----------
__global__ void k_out(const int* __restrict__ labels, float* __restrict__ out) {
    int idx = blockIdx.x * blockDim.x + threadIdx.x;
    if (idx >= D * D) return;
    int i = idx >> 10, j = idx & (D - 1);
    out[idx] = (i == j || labels[i] == labels[j]) ? 1.0f : 0.0f;
}

extern "C" void kernel_launch(void* const* d_in, const int* in_sizes, int n_in,
                              void* d_out, int out_size, void* d_ws, size_t ws_size,
                              hipStream_t stream) {
    const float* X = (const float*)d_in[0];
    const float* W = (const float*)d_in[1];

    char* ws = (char*)d_ws;
    const size_t PC_BYTES = (size_t)D * D * sizeof(float2);  // 8 MiB
    float2* pc = (float2*)ws;
    float* values_g = (float*)(ws + PC_BYTES);
    int* indices_g = (int*)(ws + PC_BYTES + 4096);
    int* labels_g = (int*)(ws + PC_BYTES + 8192);
    u32* scal = (u32*)(ws + PC_BYTES + 12288);

    hipMemsetAsync(scal, 0, 2 * sizeof(u32), stream);
    k_maxred<<<256, 256, 0, stream>>>(X, scal);
    k_init<<<(D * D) / 256, 256, 0, stream>>>(X, W, pc, scal);
    k_rowmin<<<D, 64, 0, stream>>>(pc, values_g, indices_g, scal);
    k_hac<<<1, 1024, 0, stream>>>(pc, values_g, indices_g, labels_g, scal);
    k_out<<<(D * D) / 256, 256, 0, stream>>>(labels_g, (float*)d_out);
}

// Round 5
// 4320.604 us; speedup vs baseline: 1.9087x; 1.1413x over previous
//
#include <hip/hip_runtime.h>
#include <stdint.h>

#define D 1024

typedef unsigned long long u64;
typedef unsigned int u32;

// ---------- monotonic float<->uint mapping for atomic max ----------
__device__ __forceinline__ u32 enc_f(float f) {
    u32 b = __float_as_uint(f);
    return (b & 0x80000000u) ? ~b : (b | 0x80000000u);
}
__device__ __forceinline__ float dec_f(u32 u) {
    u32 b = (u & 0x80000000u) ? (u ^ 0x80000000u) : ~u;
    return __uint_as_float(b);
}

// ---------- kernel A: max(X), max|X| ----------
__global__ void k_maxred(const float* __restrict__ X, u32* scal) {
    float mx = -INFINITY, ma = 0.f;
    int stride = gridDim.x * blockDim.x;
    for (int i = blockIdx.x * blockDim.x + threadIdx.x; i < D * D; i += stride) {
        float v = X[i];
        mx = fmaxf(mx, v);
        ma = fmaxf(ma, fabsf(v));
    }
    for (int o = 32; o; o >>= 1) {
        mx = fmaxf(mx, __shfl_xor(mx, o));
        ma = fmaxf(ma, __shfl_xor(ma, o));
    }
    if ((threadIdx.x & 63) == 0) {
        atomicMax(&scal[0], enc_f(mx));  // max_sim
        atomicMax(&scal[1], enc_f(ma));  // max|X|
    }
}

// ---------- kernel B: init dist (f32) and cross (f32) matrices ----------
__global__ void k_init(const float* __restrict__ X, const float* __restrict__ W,
                       float* __restrict__ dist, float* __restrict__ cross,
                       const u32* __restrict__ scal) {
    int idx = blockIdx.x * blockDim.x + threadIdx.x;
    if (idx >= D * D) return;
    float max_sim = dec_f(scal[0]);
    float MAXD = __fmul_rn(dec_f(scal[1]), 1000.0f);
    int i = idx >> 10, j = idx & (D - 1);
    float x = X[idx];
    // X is bitwise symmetric (0.5*(A+A^T)), so this matches max_sim - X[min][max]
    dist[idx] = (i == j) ? MAXD : __fsub_rn(max_sim, x);
    cross[idx] = (i == j) ? 0.0f : (W[idx] + W[j * D + i]);  // one addend is exactly 0
}

// ---------- kernel B2: initial per-row (min,argmin) over upper triangle ----------
__global__ void k_rowmin(const float* __restrict__ dist, float* __restrict__ values_g,
                         int* __restrict__ indices_g, const u32* __restrict__ scal) {
    int r = blockIdx.x;
    int lane = threadIdx.x;  // 64 threads = 1 wave
    float MAXD = __fmul_rn(dec_f(scal[1]), 1000.0f);
    u64 best = ((u64)__float_as_uint(MAXD) << 32);  // (MAXD, idx 0) like jnp.argmin on all-MAXD row
    const float* row = dist + (size_t)r * D;
    for (int j = lane; j < D; j += 64) {
        if (j > r) {
            u64 k = ((u64)__float_as_uint(row[j]) << 32) | (u32)j;
            if (k < best) best = k;
        }
    }
    for (int o = 32; o; o >>= 1) {
        u64 k2 = __shfl_xor(best, o);
        if (k2 < best) best = k2;
    }
    if (lane == 0) {
        values_g[r] = __uint_as_float((u32)(best >> 32));
        indices_g[r] = (int)(best & 0xffffffffu);
    }
}

// ---------- kernel C: persistent single-block HAC loop, 2 barriers/iter ----------
__global__ void __launch_bounds__(1024) k_hac(
        float* __restrict__ dist, float* __restrict__ cross,
        const float* __restrict__ values_g, const int* __restrict__ indices_g,
        int* __restrict__ labels_g, const u32* __restrict__ scal) {
    __shared__ __align__(16) float values_l[D];
    __shared__ int indices_l[D];
    __shared__ __align__(16) float newv_l[D];
    __shared__ float cs_l[D];
    __shared__ unsigned char dead_l[D];
    __shared__ int slot_l[D];   // slot_of_leaf
    __shared__ int label_l[D];
    __shared__ double within_l[D];
    __shared__ double energy_l[D];
    __shared__ int rlist[2][D];
    __shared__ int nrec[2];
    __shared__ u64 wkeys[16];
    __shared__ float s_cross12;
    __shared__ int s_takeP, s_m1P, s_labP;  // deferred cut decision (applied next iter)

    const int t = threadIdx.x;
    const int lane = t & 63, wid = t >> 6;
    const float MAXD = __fmul_rn(dec_f(scal[1]), 1000.0f);
    const u32 MAXDb = __float_as_uint(MAXD);

    values_l[t] = values_g[t];
    indices_l[t] = indices_g[t];
    cs_l[t] = 1.0f;
    dead_l[t] = 0;
    slot_l[t] = t;
    label_l[t] = t;
    within_l[t] = 0.0;
    energy_l[t] = 0.0;
    if (t == 0) { s_takeP = 0; s_m1P = -1; s_labP = 0; nrec[0] = 0; nrec[1] = 0; }
    __syncthreads();
    // boot: per-wave argmin over own 64 values -> wkeys (key = (value, row))
    {
        u64 key = ((u64)__float_as_uint(values_l[t]) << 32) | (u32)t;
        for (int o = 32; o; o >>= 1) {
            u64 k2 = __shfl_xor(key, o);
            if (k2 < key) key = k2;
        }
        if (lane == 0) wkeys[wid] = key;
    }
    __syncthreads();  // equivalent of B3 for it=0

    for (int it = 0; it < D - 1; ++it) {
        const int buf = it & 1;

        // ================= P2 =================
        // combine the 16 wave keys (broadcast LDS reads, every thread)
        u64 best = wkeys[0];
#pragma unroll
        for (int w = 1; w < 16; ++w) {
            u64 k = wkeys[w];
            if (k < best) best = k;
        }
        const int m1 = (int)(best & 0xffffffffu);
        const int m2 = indices_l[m1];  // m2 > m1 always (upper-tri argmin)
        const float cs1 = cs_l[m1], cs2 = cs_l[m2];
        const float ncs = __fadd_rn(cs1, cs2);

        // freeze m2 early (own-thread write; alive read below sees it)
        if (t == m2) {
            dead_l[m2] = 1;
            values_l[m2] = MAXD;  // vmask freeze
            indices_l[m2] = 0;    // argmin of all-MAXD row
        }
        const bool alive = !dead_l[t];

        // issue global loads ASAP; LDS bookkeeping below fills the shadow
        float d1, d2, c1, c2;
        if (alive || t == m2) {
            d1 = dist[(size_t)m1 * D + t];
            d2 = dist[(size_t)m2 * D + t];
            c1 = cross[(size_t)m1 * D + t];
            c2 = cross[(size_t)m2 * D + t];
        }

        // deferred label apply (prev iter's cut), then slot merge for this iter
        {
            int sl = slot_l[t];
            if (s_takeP && sl == s_m1P) label_l[t] = s_labP;
            if (sl == m2) slot_l[t] = m1;
        }

        float nv = MAXD, ncx;
        bool do_col = false;
        {
            if (t == m2) s_cross12 = c1;  // old cross(m1,m2), consumed post-B2
            if (alive && t != m1) {
                nv = __fdiv_rn(__fadd_rn(__fmul_rn(d1, cs1), __fmul_rn(d2, cs2)), ncs);
                ncx = c1 + c2;
                newv_l[t] = nv;                     // LDS copy of merged row
                dist[(size_t)m1 * D + t] = nv;      // row m1 (coalesced)
                cross[(size_t)m1 * D + t] = ncx;
                do_col = true;                      // col stores deferred to P3
            }
        }
        // incremental row-min maintenance (thread t == row t)
        {
            float v = values_l[t];
            if (t == m1) {
                values_l[t] = MAXD;  // transient; wave1 recomputes from newv_l
            } else if (alive && v < MAXD) {
                int idx = indices_l[t];
                if (idx == m2) {
                    rlist[buf][atomicAdd(&nrec[buf], 1)] = t;
                    values_l[t] = MAXD;
                } else if (idx == m1) {  // implies t < m1
                    if (nv <= v) values_l[t] = nv;  // lowest-index tie preserved
                    else {
                        rlist[buf][atomicAdd(&nrec[buf], 1)] = t;
                        values_l[t] = MAXD;
                    }
                } else if (t < m1) {  // col m1 got nv in row t
                    if (nv < v) { values_l[t] = nv; indices_l[t] = m1; }
                    else if (nv == v && m1 < idx) indices_l[t] = m1;  // jnp.argmin tie-break
                }
            }
        }
        __syncthreads();  // B2 (publishes LDS; drains row loads/stores)

        // ================= P3 =================
        // scattered col stores first so their drain overlaps the scans
        if (do_col) {
            dist[(size_t)t * D + m1] = nv;
            cross[(size_t)t * D + m1] = ncx;
        }
        if (t == m1) cs_l[m1] = ncs;  // nobody reads cs_l in P3
        const int n = nrec[buf];
        if (t == 0) nrec[1 - buf] = 0;

        u64 wkey = ~0ull;
        if (wid == 0) {
            if (lane == 0) {
                // cut decision (f64 accumulators)
                double merge_e = within_l[m1] + within_l[m2] + (double)s_cross12;
                double e_sum = energy_l[m1] + energy_l[m2];
                int take = (merge_e >= e_sum) ? 1 : 0;
                within_l[m1] = merge_e;
                energy_l[m1] = take ? merge_e : e_sum;
                s_takeP = take;
                s_m1P = m1;
                s_labP = D + it;
            }
            // full argmin scan of values_l (transient-MAXD rows' true keys come
            // from wave1 / rescan waves — min-combine is exact)
            const float4* v4 = (const float4*)values_l;
            u64 bb = ~0ull;
#pragma unroll
            for (int c = 0; c < 4; ++c) {
                int fi = lane + 64 * c;
                float4 q = v4[fi];
                int b = fi << 2;
                u64 k;
                k = ((u64)__float_as_uint(q.x) << 32) | (u32)(b + 0); if (k < bb) bb = k;
                k = ((u64)__float_as_uint(q.y) << 32) | (u32)(b + 1); if (k < bb) bb = k;
                k = ((u64)__float_as_uint(q.z) << 32) | (u32)(b + 2); if (k < bb) bb = k;
                k = ((u64)__float_as_uint(q.w) << 32) | (u32)(b + 3); if (k < bb) bb = k;
            }
            for (int o = 32; o; o >>= 1) {
                u64 k2 = __shfl_xor(bb, o);
                if (k2 < bb) bb = k2;
            }
            wkey = bb;
        } else if (wid == 1) {
            // row m1's new min from LDS newv_l (no global read)
            u64 bb = ((u64)MAXDb << 32);  // (MAXD, col 0)
            const float4* nv4 = (const float4*)newv_l;
            for (int c = lane; c < D / 4; c += 64) {
                float4 q = nv4[c];
                int j0 = c << 2;
#pragma unroll
                for (int e = 0; e < 4; ++e) {
                    int j = j0 + e;
                    float dv = (e == 0) ? q.x : (e == 1) ? q.y : (e == 2) ? q.z : q.w;
                    if (j > m1 && !dead_l[j]) {
                        u64 k = ((u64)__float_as_uint(dv) << 32) | (u32)j;
                        if (k < bb) bb = k;
                    }
                }
            }
            for (int o = 32; o; o >>= 1) {
                u64 k2 = __shfl_xor(bb, o);
                if (k2 < bb) bb = k2;
            }
            if (lane == 0) {
                values_l[m1] = __uint_as_float((u32)(bb >> 32));
                indices_l[m1] = (int)(bb & 0xffffffffu);
            }
            wkey = (bb & 0xffffffff00000000ull) | (u32)m1;  // key payload = ROW
        } else {
            // residual rescans (rows whose argmin retired/增), one wave per row
            for (int q = wid - 2; q < n; q += 14) {
                const int r = rlist[buf][q];
                const float subst = newv_l[r];  // col-m1 value (store in flight)
                u64 bb = ((u64)MAXDb << 32);    // (MAXD, col 0)
                const float4* row4 = (const float4*)(dist + (size_t)r * D);
                for (int c = lane; c < D / 4; c += 64) {
                    float4 q4 = row4[c];
                    int j0 = c << 2;
#pragma unroll
                    for (int e = 0; e < 4; ++e) {
                        int j = j0 + e;
                        float dv = (e == 0) ? q4.x : (e == 1) ? q4.y : (e == 2) ? q4.z : q4.w;
                        if (j == m1) dv = subst;
                        if (j > r && !dead_l[j]) {
                            u64 k = ((u64)__float_as_uint(dv) << 32) | (u32)j;
                            if (k < bb) bb = k;
                        }
                    }
                }
                for (int o = 32; o; o >>= 1) {
                    u64 k2 = __shfl_xor(bb, o);
                    if (k2 < bb) bb = k2;
                }
                if (lane == 0) {
                    values_l[r] = __uint_as_float((u32)(bb >> 32));
                    indices_l[r] = (int)(bb & 0xffffffffu);
                }
                u64 rowkey = (bb & 0xffffffff00000000ull) | (u32)r;  // payload = ROW
                if (rowkey < wkey) wkey = rowkey;
            }
        }
        if (lane == 0) wkeys[wid] = wkey;
        __syncthreads();  // B3 (publishes argmin keys; drains col stores + loads)
    }

    // apply the final iteration's deferred cut, then emit labels
    {
        int lab = label_l[t];
        if (s_takeP && slot_l[t] == s_m1P) lab = s_labP;
        labels_g[t] = lab;
    }
}

// ---------- kernel D: R[a][b] = (a==b) || (label[a]==label[b]) ----------
__global__ void k_out(const int* __restrict__ labels, float* __restrict__ out) {
    int idx = blockIdx.x * blockDim.x + threadIdx.x;
    if (idx >= D * D) return;
    int i = idx >> 10, j = idx & (D - 1);
    out[idx] = (i == j || labels[i] == labels[j]) ? 1.0f : 0.0f;
}

extern "C" void kernel_launch(void* const* d_in, const int* in_sizes, int n_in,
                              void* d_out, int out_size, void* d_ws, size_t ws_size,
                              hipStream_t stream) {
    const float* X = (const float*)d_in[0];
    const float* W = (const float*)d_in[1];

    char* ws = (char*)d_ws;
    const size_t MAT_BYTES = (size_t)D * D * sizeof(float);  // 4 MiB each
    float* dist = (float*)ws;
    float* cross = (float*)(ws + MAT_BYTES);
    float* values_g = (float*)(ws + 2 * MAT_BYTES);
    int* indices_g = (int*)(ws + 2 * MAT_BYTES + 4096);
    int* labels_g = (int*)(ws + 2 * MAT_BYTES + 8192);
    u32* scal = (u32*)(ws + 2 * MAT_BYTES + 12288);

    hipMemsetAsync(scal, 0, 2 * sizeof(u32), stream);
    k_maxred<<<256, 256, 0, stream>>>(X, scal);
    k_init<<<(D * D) / 256, 256, 0, stream>>>(X, W, dist, cross, scal);
    k_rowmin<<<D, 64, 0, stream>>>(dist, values_g, indices_g, scal);
    k_hac<<<1, 1024, 0, stream>>>(dist, cross, values_g, indices_g, labels_g, scal);
    k_out<<<(D * D) / 256, 256, 0, stream>>>(labels_g, (float*)d_out);
}